// Round 2
// baseline (824.079 us; speedup 1.0000x reference)
//
#include <hip/hip_runtime.h>

#define STATE 81
#define NROWS 64          // rows per block
#define OBSW  243
#define AFW   405

// The 5 inflow sources of destination state d (verified: every d has exactly 5):
//   stay: 5d
//   vertical:  (r<8) ? from-below 5(d+9)+1 : bounce 5d+2
//              (r>0) ? from-above 5(d-9)+2 : bounce 5d+1
//   horizontal:(c<8) ? from-right 5(d+1)+3 : bounce 5d+4
//              (c>0) ? from-left  5(d-1)+4 : bounce 5d+3
__device__ __forceinline__ void srcs_for(int d, int* s) {
    int r = d / 9;
    int c = d - r * 9;
    s[0] = 5 * d;
    s[1] = (r < 8) ? 5 * (d + 9) + 1 : 5 * d + 2;
    s[2] = (r > 0) ? 5 * (d - 9) + 2 : 5 * d + 1;
    s[3] = (c < 8) ? 5 * (d + 1) + 3 : 5 * d + 4;
    s[4] = (c > 0) ? 5 * (d - 1) + 4 : 5 * d + 3;
}

// Layer 1 quarter: outputs [8W, 8W+8). W compile-time -> W1 offsets constant ->
// uniform base -> s_load weights (SGPR-operand v_fmac).
template <int W>
__device__ __forceinline__ void layer1(const float* __restrict__ snsc,
                                       float* __restrict__ x1T,
                                       const float* __restrict__ W1, int row) {
    float x1[8];
#pragma unroll
    for (int j = 0; j < 8; ++j) x1[j] = 0.f;
#pragma unroll
    for (int d = 0; d < STATE; ++d) {
        float v = snsc[row * STATE + d];
#pragma unroll
        for (int j = 0; j < 8; ++j)
            x1[j] = fmaf(v, W1[d * 32 + W * 8 + j], x1[j]);
    }
#pragma unroll
    for (int j = 0; j < 8; ++j)
        x1T[(W * 8 + j) * 65 + row] = fmaxf(x1[j], 0.f);
}

template <int W>
__device__ __forceinline__ void layer2(const float* __restrict__ x1T,
                                       float* __restrict__ x2,
                                       const float* __restrict__ W2, int row) {
#pragma unroll
    for (int j = 0; j < 8; ++j) x2[j] = 0.f;
#pragma unroll
    for (int k = 0; k < 32; ++k) {
        float v = x1T[k * 65 + row];
#pragma unroll
        for (int j = 0; j < 8; ++j)
            x2[j] = fmaf(v, W2[k * 32 + W * 8 + j], x2[j]);
    }
}

__global__ __launch_bounds__(256, 5) void grid_vpn_kernel(
    const float* __restrict__ obs, const float* __restrict__ af,
    const float* __restrict__ W1, const float* __restrict__ W2,
    const float* __restrict__ W3, const float* __restrict__ b3,
    float* __restrict__ out, int B)
{
    __shared__ float snsc[NROWS * STATE];   // 20736 B
    __shared__ float x1T[32 * 65];          //  8320 B (reused for x2)
    __shared__ float sir[NROWS];            //   256 B

    const int t = threadIdx.x;
    const int lane = t & 63;
    const int w = t >> 6;                   // wave id 0..3
    const int rowblk = blockIdx.x * NROWS;

    const bool has2 = lane < (STATE - 64);  // lanes 0..16 also handle d = lane+64
    int s0[5], s1[5];
    srcs_for(lane, s0);
    srcs_for(has2 ? lane + 64 : lane, s1);

    // ---- gather phase: wave w owns rows w, w+4, w+8, ... (16 rows) ----
#pragma unroll 2
    for (int i = 0; i < 16; ++i) {
        const int rl = w + 4 * i;
        const int row = rowblk + rl;
        const float* afr = af + (size_t)row * AFW;
        const float* dem = obs + (size_t)row * OBSW + 2 * STATE;

        float acc = afr[s0[0]] + afr[s0[1]] + afr[s0[2]] + afr[s0[3]] + afr[s0[4]];
        float m = fminf(acc, dem[lane]);
        float acc2 = 0.f, m2 = 0.f;
        if (has2) {
            acc2 = afr[s1[0]] + afr[s1[1]] + afr[s1[2]] + afr[s1[3]] + afr[s1[4]];
            m2 = fminf(acc2, dem[64 + lane]);
        }
        snsc[rl * STATE + lane] = acc;
        if (has2) snsc[rl * STATE + 64 + lane] = acc2;

        float irv = m + m2;
#pragma unroll
        for (int off = 32; off; off >>= 1) irv += __shfl_xor(irv, off, 64);
        if (lane == 0) sir[rl] = irv;
    }
    __syncthreads();

    // ---- coalesced nsc writeback (5184 floats contiguous per block) ----
    {
        float* onsc = out + 3 * (size_t)B + (size_t)rowblk * STATE;
#pragma unroll
        for (int k = 0; k < 20; ++k) onsc[t + 256 * k] = snsc[t + 256 * k];
        if (t < NROWS * STATE - 256 * 20) onsc[t + 5120] = snsc[t + 5120];
    }

    // ---- MLP: thread-per-row (row = lane), wave w computes output quarter w ----
    const int row = lane;
    if      (w == 0) layer1<0>(snsc, x1T, W1, row);
    else if (w == 1) layer1<1>(snsc, x1T, W1, row);
    else if (w == 2) layer1<2>(snsc, x1T, W1, row);
    else             layer1<3>(snsc, x1T, W1, row);
    __syncthreads();

    float x2[8];
    if      (w == 0) layer2<0>(x1T, x2, W2, row);
    else if (w == 1) layer2<1>(x1T, x2, W2, row);
    else if (w == 2) layer2<2>(x1T, x2, W2, row);
    else             layer2<3>(x1T, x2, W2, row);
    __syncthreads();   // all layer-2 reads of x1T done

#pragma unroll
    for (int j = 0; j < 8; ++j)
        x1T[(w * 8 + j) * 65 + row] = fmaxf(x2[j], 0.f);   // reuse buffer for x2
    __syncthreads();

    if (w == 0) {
        float nr = b3[0];
#pragma unroll
        for (int k = 0; k < 32; ++k)
            nr = fmaf(x1T[k * 65 + row], W3[k], nr);
        const float ir = sir[row];
        const size_t b = rowblk + row;
        out[b] = ir + nr;
        out[(size_t)B + b] = ir;
        out[2 * (size_t)B + b] = nr;
    }
}

extern "C" void kernel_launch(void* const* d_in, const int* in_sizes, int n_in,
                              void* d_out, int out_size, void* d_ws, size_t ws_size,
                              hipStream_t stream) {
    const float* obs = (const float*)d_in[0];
    const float* ac  = (const float*)d_in[1];
    const float* W1  = (const float*)d_in[2];
    const float* W2  = (const float*)d_in[3];
    const float* W3  = (const float*)d_in[4];
    const float* b3  = (const float*)d_in[5];
    float* out = (float*)d_out;

    int B = in_sizes[0] / OBSW;
    int grid = B / NROWS;                   // B = 131072 -> 2048 blocks
    hipLaunchKernelGGL(grid_vpn_kernel, dim3(grid), dim3(256), 0, stream,
                       obs, ac, W1, W2, W3, b3, out, B);
}

// Round 3
// 807.323 us; speedup vs baseline: 1.0208x; 1.0208x over previous
//
#include <hip/hip_runtime.h>

#define STATE 81
#define NROWS 64            // rows per block
#define GROUP 8             // rows per staged group
#define NG (NROWS / GROUP)  // 8 groups
#define OBSW 243
#define AFW  405
#define GDW (GROUP * AFW)   // 3240 dwords per staged group
#define GF4 (GDW / 4)       // 810 float4 per group (rowblk*405 and 3240 are mult of 4)

// The 5 inflow sources of destination state d (every d has exactly 5):
__device__ __forceinline__ void srcs_for(int d, int* s) {
    int r = d / 9;
    int c = d - r * 9;
    s[0] = 5 * d;
    s[1] = (r < 8) ? 5 * (d + 9) + 1 : 5 * d + 2;
    s[2] = (r > 0) ? 5 * (d - 9) + 2 : 5 * d + 1;
    s[3] = (c < 8) ? 5 * (d + 1) + 3 : 5 * d + 4;
    s[4] = (c > 0) ? 5 * (d - 1) + 4 : 5 * d + 3;
}

// Layer 1 quarter W: outputs [8W, 8W+8). Constant W1 offsets -> s_load weights.
template <int W>
__device__ __forceinline__ void layer1(const float* __restrict__ snsc,
                                       float* __restrict__ x1T,
                                       const float* __restrict__ W1, int row) {
    float x1[8];
#pragma unroll
    for (int j = 0; j < 8; ++j) x1[j] = 0.f;
#pragma unroll
    for (int d = 0; d < STATE; ++d) {
        float v = snsc[row * STATE + d];
#pragma unroll
        for (int j = 0; j < 8; ++j)
            x1[j] = fmaf(v, W1[d * 32 + W * 8 + j], x1[j]);
    }
#pragma unroll
    for (int j = 0; j < 8; ++j)
        x1T[(W * 8 + j) * 65 + row] = fmaxf(x1[j], 0.f);
}

template <int W>
__device__ __forceinline__ void layer2(const float* __restrict__ x1T,
                                       float* __restrict__ x2,
                                       const float* __restrict__ W2, int row) {
#pragma unroll
    for (int j = 0; j < 8; ++j) x2[j] = 0.f;
#pragma unroll
    for (int k = 0; k < 32; ++k) {
        float v = x1T[k * 65 + row];
#pragma unroll
        for (int j = 0; j < 8; ++j)
            x2[j] = fmaf(v, W2[k * 32 + W * 8 + j], x2[j]);
    }
}

__global__ __launch_bounds__(256, 4) void grid_vpn_kernel(
    const float* __restrict__ obs, const float* __restrict__ af,
    const float* __restrict__ W1, const float* __restrict__ W2,
    const float* __restrict__ W3, const float* __restrict__ b3,
    float* __restrict__ out, int B)
{
    __shared__ float s_af[GDW];            // 12960 B; reused as x1T/x2 in MLP phase
    __shared__ float snsc[NROWS * STATE];  // 20736 B
    __shared__ float sir[NROWS];           //   256 B

    const int t = threadIdx.x;
    const int lane = t & 63;
    const int w = t >> 6;
    const int rowblk = blockIdx.x * NROWS;

    const bool has2 = lane < (STATE - 64);   // lanes 0..16 also handle d = lane+64
    int s0[5], s1[5];
    srcs_for(lane, s0);
    srcs_for(has2 ? lane + 64 : lane, s1);

    const float4* g4 = (const float4*)(af + (size_t)rowblk * AFW);
    const bool tail = t < (GF4 - 768);       // t < 42

    // ---- prefetch group 0 into VGPRs (coalesced float4) ----
    float4 pf0 = g4[t], pf1 = g4[t + 256], pf2 = g4[t + 512];
    float4 pf3 = tail ? g4[t + 768] : float4{0, 0, 0, 0};

    for (int g = 0; g < NG; ++g) {
        // commit prefetched group into LDS
        float4* s4 = (float4*)s_af;
        s4[t] = pf0; s4[t + 256] = pf1; s4[t + 512] = pf2;
        if (tail) s4[t + 768] = pf3;
        __syncthreads();

        // prefetch next group (in flight during compute)
        if (g + 1 < NG) {
            const float4* n4 = g4 + (size_t)(g + 1) * GF4;
            pf0 = n4[t]; pf1 = n4[t + 256]; pf2 = n4[t + 512];
            if (tail) pf3 = n4[t + 768];
        }

        // compute: wave w handles rows w*2, w*2+1 of this group
#pragma unroll
        for (int i = 0; i < 2; ++i) {
            const int rg = w * 2 + i;
            const int rl = g * GROUP + rg;
            const size_t row = rowblk + rl;
            const float* afr = s_af + rg * AFW;
            const float* dem = obs + row * OBSW + 2 * STATE;

            float dm = dem[lane];
            float dm2 = has2 ? dem[64 + lane] : 0.f;

            float acc = afr[s0[0]] + afr[s0[1]] + afr[s0[2]] + afr[s0[3]] + afr[s0[4]];
            float acc2 = 0.f;
            if (has2)
                acc2 = afr[s1[0]] + afr[s1[1]] + afr[s1[2]] + afr[s1[3]] + afr[s1[4]];

            snsc[rl * STATE + lane] = acc;
            if (has2) snsc[rl * STATE + 64 + lane] = acc2;

            float irv = fminf(acc, dm) + (has2 ? fminf(acc2, dm2) : 0.f);
#pragma unroll
            for (int off = 32; off; off >>= 1) irv += __shfl_xor(irv, off, 64);
            if (lane == 0) sir[rl] = irv;
        }
        __syncthreads();   // compute done -> s_af free for next group's commit
    }

    // ---- coalesced nsc writeback: 5184 dwords = 1296 float4 (aligned) ----
    {
        float4* o4 = (float4*)(out + 3 * (size_t)B + (size_t)rowblk * STATE);
        const float4* s4 = (const float4*)snsc;
#pragma unroll
        for (int k = 0; k < 5; ++k) o4[t + 256 * k] = s4[t + 256 * k];
        if (t < 1296 - 1280) o4[t + 1280] = s4[t + 1280];
    }

    // ---- MLP: thread-per-row (row = lane), wave w computes output quarter w ----
    float* x1T = s_af;   // 8320 B needed <= 12960 B available
    const int row = lane;
    if      (w == 0) layer1<0>(snsc, x1T, W1, row);
    else if (w == 1) layer1<1>(snsc, x1T, W1, row);
    else if (w == 2) layer1<2>(snsc, x1T, W1, row);
    else             layer1<3>(snsc, x1T, W1, row);
    __syncthreads();

    float x2[8];
    if      (w == 0) layer2<0>(x1T, x2, W2, row);
    else if (w == 1) layer2<1>(x1T, x2, W2, row);
    else if (w == 2) layer2<2>(x1T, x2, W2, row);
    else             layer2<3>(x1T, x2, W2, row);
    __syncthreads();   // all layer-2 reads of x1T done

#pragma unroll
    for (int j = 0; j < 8; ++j)
        x1T[(w * 8 + j) * 65 + row] = fmaxf(x2[j], 0.f);   // buffer now holds x2
    __syncthreads();

    if (w == 0) {
        float nr = b3[0];
#pragma unroll
        for (int k = 0; k < 32; ++k)
            nr = fmaf(x1T[k * 65 + row], W3[k], nr);
        const float ir = sir[row];
        const size_t b = rowblk + row;
        out[b] = ir + nr;
        out[(size_t)B + b] = ir;
        out[2 * (size_t)B + b] = nr;
    }
}

extern "C" void kernel_launch(void* const* d_in, const int* in_sizes, int n_in,
                              void* d_out, int out_size, void* d_ws, size_t ws_size,
                              hipStream_t stream) {
    const float* obs = (const float*)d_in[0];
    const float* ac  = (const float*)d_in[1];
    const float* W1  = (const float*)d_in[2];
    const float* W2  = (const float*)d_in[3];
    const float* W3  = (const float*)d_in[4];
    const float* b3  = (const float*)d_in[5];
    float* out = (float*)d_out;

    int B = in_sizes[0] / OBSW;
    int grid = B / NROWS;   // 131072 / 64 = 2048
    hipLaunchKernelGGL(grid_vpn_kernel, dim3(grid), dim3(256), 0, stream,
                       obs, ac, W1, W2, W3, b3, out, B);
}